// Round 1
// baseline (226.662 us; speedup 1.0000x reference)
//
#include <hip/hip_runtime.h>
#include <math.h>

#define BB 16
#define CC 6
#define QQ 256
#define TT 256
#define DD 256
#define NPAIR 15   // C*(C-1)/2 for C=6

// ws float accumulator slots
#define ACC_SS     0
#define ACC_ENT    1
#define ACC_SCORE  2
#define ACC_BOX    3
#define ACC_PAIR   4
#define ACC_CONS   5
#define ACC_CONSCNT 6
#define ACC_CAMCNT 7
#define ACC_QVCNT  8

// ws layout (bytes):
//   [0,    256)  float accumulators
//   [256,  352)  cam_c  uchar[96]
//   [512,  25088) tm_c  uchar[24576]
//   [25088,123392) qids int[24576]

__device__ __forceinline__ float block_sum256(float v, float* s_red) {
    #pragma unroll
    for (int off = 32; off > 0; off >>= 1) v += __shfl_xor(v, off, 64);
    __syncthreads();
    if ((threadIdx.x & 63) == 0) s_red[threadIdx.x >> 6] = v;
    __syncthreads();
    return s_red[0] + s_red[1] + s_red[2] + s_red[3];
}

// ---------------------------------------------------------------------------
// Kernel 0: detect bool storage format (int32 / uint8 / float32) from the
// target_mask byte pattern, then canonicalize both masks to uchar 0/1.
// ---------------------------------------------------------------------------
__global__ void k_masks(const void* __restrict__ cam_raw,
                        const void* __restrict__ tm_raw,
                        unsigned char* __restrict__ cam_c,
                        unsigned char* __restrict__ tm_c) {
    const int n_tm = BB * CC * QQ;   // 24576 elements; inspect that many BYTES (safe in all formats)
    const int n_cam = BB * CC;
    const unsigned char* tb = (const unsigned char*)tm_raw;
    int cf = 0, cm = 0;
    for (int i = threadIdx.x; i < n_tm; i += blockDim.x) {
        unsigned char v = tb[i];
        int r = i & 3;
        if (r == 3 && v == 0x3F) cf++;      // signature of 1.0f high byte
        if (r != 0 && v != 0) cm++;         // nonzero misaligned byte => byte-packed
    }
    __shared__ int s_cf, s_cm;
    if (threadIdx.x == 0) { s_cf = 0; s_cm = 0; }
    __syncthreads();
    if (cf) atomicAdd(&s_cf, cf);
    if (cm) atomicAdd(&s_cm, cm);
    __syncthreads();
    int fmt = (s_cf > 16) ? 2 : ((s_cm > 0) ? 1 : 0);  // 0=int32 1=uint8 2=float32
    for (int i = threadIdx.x; i < n_tm; i += blockDim.x) {
        unsigned char v;
        if (fmt == 2)      v = (((const float*)tm_raw)[i] != 0.0f);
        else if (fmt == 1) v = (tb[i] != 0);
        else               v = (((const int*)tm_raw)[i] != 0);
        tm_c[i] = v;
    }
    for (int i = threadIdx.x; i < n_cam; i += blockDim.x) {
        unsigned char v;
        if (fmt == 2)      v = (((const float*)cam_raw)[i] != 0.0f);
        else if (fmt == 1) v = (((const unsigned char*)cam_raw)[i] != 0);
        else               v = (((const int*)cam_raw)[i] != 0);
        cam_c[i] = v;
    }
}

// ---------------------------------------------------------------------------
// Kernel 1: per-(b,c) pack (stable targets-first order) + score/box/pair
// losses + qids for the consistency kernel. One block of 256 per (b,c).
// ---------------------------------------------------------------------------
__global__ __launch_bounds__(256)
void k_pack(const float* __restrict__ det_scores,
            const float* __restrict__ det_boxes,
            const float* __restrict__ assoc,
            const float* __restrict__ boxes,
            const unsigned char* __restrict__ cam_c,
            const unsigned char* __restrict__ tm_c,
            const int* __restrict__ ids,
            const int* __restrict__ img_h_p,
            const int* __restrict__ img_w_p,
            int* __restrict__ qids,
            float* __restrict__ acc) {
    const int bc = blockIdx.x;      // b*CC + c
    const int t = threadIdx.x;      // 0..255 (query index)
    __shared__ int s_scan[QQ];
    __shared__ int s_sids[QQ];
    __shared__ float s_red[4];

    const int cam = cam_c[bc];
    const int tm = tm_c[bc * QQ + t];

    // inclusive prefix sum of tm (Hillis-Steele)
    s_scan[t] = tm;
    __syncthreads();
    for (int off = 1; off < QQ; off <<= 1) {
        int u = (t >= off) ? s_scan[t - off] : 0;
        __syncthreads();
        s_scan[t] += u;
        __syncthreads();
    }
    const int count = s_scan[QQ - 1];
    const int excl = s_scan[t] - tm;
    const int rank = tm ? excl : (count + (t - excl));   // stable partition rank

    // scatter sorted ids: sids[rank(q)] = ids[q]  (rank is a permutation)
    s_sids[rank] = ids[bc * QQ + t];
    __syncthreads();

    // thread t plays packed-slot j = t for score/pair, original-q = t for box
    const int j = t;
    const int qv = (j < count) && cam;
    const int qid = qv ? s_sids[j] : -1;
    qids[bc * QQ + j] = qid;

    float score_sum = 0.0f, box_sum = 0.0f, pair_sum = 0.0f;

    if (cam) {
        float p = det_scores[(size_t)bc * QQ + j];
        p = fminf(fmaxf(p, 1e-6f), 1.0f - 1e-6f);
        score_sum = (j < count) ? -logf(p) : -log1pf(-p);
    }
    if (qv) {
        int slot = qid & (TT - 1);          // qid >= 0, TT power of 2
        float a = assoc[((size_t)bc * QQ + j) * TT + slot];
        pair_sum = -logf(fmaxf(a, 1e-8f));
    }
    if (tm && cam) {
        // this original query q=t landed at packed slot jj=rank
        const int jj = rank;
        const float iw = (float)img_w_p[0], ih = (float)img_h_p[0];
        const float* bx = boxes + ((size_t)bc * QQ + t) * 4;
        const float* db = det_boxes + ((size_t)bc * QQ + jj) * 4;
        float b0 = fminf(fmaxf(bx[0] / iw, 0.0f), 1.0f);
        float b1 = fminf(fmaxf(bx[1] / ih, 0.0f), 1.0f);
        float b2 = fminf(fmaxf(bx[2] / iw, 0.0f), 1.0f);
        float b3 = fminf(fmaxf(bx[3] / ih, 0.0f), 1.0f);
        box_sum = fabsf(db[0] - b0) + fabsf(db[1] - b1) +
                  fabsf(db[2] - b2) + fabsf(db[3] - b3);
    }

    float v;
    v = block_sum256(score_sum, s_red); if (t == 0) atomicAdd(&acc[ACC_SCORE], v);
    v = block_sum256(box_sum,   s_red); if (t == 0) atomicAdd(&acc[ACC_BOX], v);
    v = block_sum256(pair_sum,  s_red); if (t == 0) atomicAdd(&acc[ACC_PAIR], v);
    if (t == 0 && cam) {
        atomicAdd(&acc[ACC_CAMCNT], 1.0f);
        atomicAdd(&acc[ACC_QVCNT], (float)count);
    }
}

// ---------------------------------------------------------------------------
// Kernel 2: fused det_norm sum-of-squares + cam-masked entropy sum.
// Both arrays are B*C*Q*256 floats; float4 grid-stride.
// ---------------------------------------------------------------------------
__global__ __launch_bounds__(256)
void k_big(const float4* __restrict__ tok, const float4* __restrict__ asc,
           const unsigned char* __restrict__ cam_c, float* __restrict__ acc) {
    const long n4 = (long)BB * CC * QQ * DD / 4;   // 1572864
    float ss = 0.0f, ent = 0.0f;
    for (long i = (long)blockIdx.x * blockDim.x + threadIdx.x; i < n4;
         i += (long)gridDim.x * blockDim.x) {
        float4 tv = tok[i];
        ss += tv.x * tv.x + tv.y * tv.y + tv.z * tv.z + tv.w * tv.w;
        int bc = (int)(i >> 14);                   // (Q*T/4) = 16384 float4 per (b,c)
        if (cam_c[bc]) {
            float4 a = asc[i];
            ent -= a.x * logf(fmaxf(a.x, 1e-8f));
            ent -= a.y * logf(fmaxf(a.y, 1e-8f));
            ent -= a.z * logf(fmaxf(a.z, 1e-8f));
            ent -= a.w * logf(fmaxf(a.w, 1e-8f));
        }
    }
    __shared__ float s_red[4];
    float v;
    v = block_sum256(ss, s_red);  if (threadIdx.x == 0) atomicAdd(&acc[ACC_SS], v);
    v = block_sum256(ent, s_red); if (threadIdx.x == 0) atomicAdd(&acc[ACC_ENT], v);
}

// ---------------------------------------------------------------------------
// Kernel 3: consistency term. One block per (b, c<d pair); 4 waves, each
// wave owns q's strided by 4; lanes split T into float4s. Matches found by
// wave-wide ballot over qids of camera d.
// ---------------------------------------------------------------------------
__global__ __launch_bounds__(256)
void k_cons(const float* __restrict__ assoc, const int* __restrict__ qids,
            float* __restrict__ acc) {
    const int b = blockIdx.x / NPAIR;
    int pi = blockIdx.x % NPAIR;
    int c = 0, d = 1;
    {
        int k = pi;
        for (c = 0; c < CC - 1; c++) {
            int span = CC - 1 - c;
            if (k < span) { d = c + 1 + k; break; }
            k -= span;
        }
    }
    __shared__ int s_qc[QQ];
    __shared__ int s_qd[QQ];
    const int t = threadIdx.x;
    s_qc[t] = qids[(b * CC + c) * QQ + t];
    s_qd[t] = qids[(b * CC + d) * QQ + t];
    __syncthreads();

    const int lane = t & 63;
    const int wave = t >> 6;
    const int qd0 = s_qd[lane];
    const int qd1 = s_qd[64 + lane];
    const int qd2 = s_qd[128 + lane];
    const int qd3 = s_qd[192 + lane];
    const float4* assoc_c = (const float4*)(assoc + ((size_t)(b * CC + c) * QQ) * TT);
    const float4* assoc_d = (const float4*)(assoc + ((size_t)(b * CC + d) * QQ) * TT);

    float term_sum = 0.0f;
    int nval = 0;
    for (int q = wave; q < QQ; q += 4) {
        int id = s_qc[q];                       // wave-uniform
        if (id < 0) continue;
        unsigned long long m0 = __ballot(qd0 == id);
        unsigned long long m1 = __ballot(qd1 == id);
        unsigned long long m2 = __ballot(qd2 == id);
        unsigned long long m3 = __ballot(qd3 == id);
        int cnt = __popcll(m0) + __popcll(m1) + __popcll(m2) + __popcll(m3);
        if (cnt == 0) continue;
        float4 r = assoc_c[(size_t)q * (TT / 4) + lane];
        float ax = 0.0f, ay = 0.0f, az = 0.0f, aw = 0.0f;
        unsigned long long mm[4] = {m0, m1, m2, m3};
        #pragma unroll
        for (int kk = 0; kk < 4; kk++) {
            unsigned long long m = mm[kk];
            while (m) {
                int p = kk * 64 + __builtin_ctzll(m);
                m &= m - 1;
                float4 v = assoc_d[(size_t)p * (TT / 4) + lane];
                ax += v.x; ay += v.y; az += v.z; aw += v.w;
            }
        }
        float inv = 1.0f / (float)cnt;
        float dx = r.x - ax * inv, dy = r.y - ay * inv;
        float dz = r.z - az * inv, dw = r.w - aw * inv;
        float s = dx * dx + dy * dy + dz * dz + dw * dw;
        #pragma unroll
        for (int off = 32; off > 0; off >>= 1) s += __shfl_xor(s, off, 64);
        term_sum += s;
        nval++;
    }
    if (lane == 0) {
        atomicAdd(&acc[ACC_CONS], term_sum * (1.0f / TT));
        atomicAdd(&acc[ACC_CONSCNT], (float)nval);
    }
}

// ---------------------------------------------------------------------------
// Kernel 4: finalize — combine accumulators into the 6 outputs.
// ---------------------------------------------------------------------------
__global__ void k_fin(const float* __restrict__ acc, float* __restrict__ out) {
    float ss = acc[ACC_SS], ent = acc[ACC_ENT], score = acc[ACC_SCORE];
    float box = acc[ACC_BOX], pair = acc[ACC_PAIR], cons = acc[ACC_CONS];
    float conscnt = acc[ACC_CONSCNT], camcnt = acc[ACC_CAMCNT], qvcnt = acc[ACC_QVCNT];

    float det_norm = ss / (float)((long)BB * CC * QQ * DD);
    float denom_cam = fmaxf(camcnt * (float)QQ, 1.0f);
    float score_loss = score / denom_cam;
    float box_loss = box / fmaxf(4.0f * qvcnt, 1.0f);
    float det_sup = score_loss + box_loss;
    float ent_loss = ent / denom_cam;
    float pair_loss = pair / fmaxf(qvcnt, 1.0f);
    float cons_loss = cons / fmaxf(conscnt, 1.0f);
    float total = det_norm + det_sup + ent_loss + pair_loss + cons_loss;

    out[0] = total;
    out[1] = det_norm;
    out[2] = det_sup;
    out[3] = ent_loss;
    out[4] = pair_loss;
    out[5] = cons_loss;
}

extern "C" void kernel_launch(void* const* d_in, const int* in_sizes, int n_in,
                              void* d_out, int out_size, void* d_ws, size_t ws_size,
                              hipStream_t stream) {
    const float* det_tokens = (const float*)d_in[0];
    const float* det_scores = (const float*)d_in[1];
    const float* det_boxes  = (const float*)d_in[2];
    const float* assoc      = (const float*)d_in[3];
    const float* boxes      = (const float*)d_in[4];
    const void*  cam_raw    = d_in[5];
    const void*  tm_raw     = d_in[6];
    const int*   ids        = (const int*)d_in[7];
    const int*   img_h      = (const int*)d_in[8];
    const int*   img_w      = (const int*)d_in[9];

    float* acc = (float*)d_ws;
    unsigned char* cam_c = (unsigned char*)d_ws + 256;
    unsigned char* tm_c  = (unsigned char*)d_ws + 512;
    int* qids = (int*)((char*)d_ws + 25088);

    hipMemsetAsync(d_ws, 0, 256, stream);   // zero accumulators (ws is poisoned each call)

    k_masks<<<1, 256, 0, stream>>>(cam_raw, tm_raw, cam_c, tm_c);
    k_pack<<<BB * CC, 256, 0, stream>>>(det_scores, det_boxes, assoc, boxes,
                                        cam_c, tm_c, ids, img_h, img_w, qids, acc);
    k_big<<<1024, 256, 0, stream>>>((const float4*)det_tokens, (const float4*)assoc,
                                    cam_c, acc);
    k_cons<<<BB * NPAIR, 256, 0, stream>>>(assoc, qids, acc);
    k_fin<<<1, 1, 0, stream>>>(acc, (float*)d_out);
}

// Round 2
// 198.714 us; speedup vs baseline: 1.1406x; 1.1406x over previous
//
#include <hip/hip_runtime.h>
#include <math.h>

#define BB 16
#define CC 6
#define QQ 256
#define TT 256
#define DD 256
#define NPAIR 15   // C*(C-1)/2 for C=6

// ws float accumulator slots
#define ACC_SS      0
#define ACC_ENT     1
#define ACC_SCORE   2
#define ACC_BOX     3
#define ACC_PAIR    4
#define ACC_CONS    5
#define ACC_CONSCNT 6
#define ACC_CAMCNT  7
#define ACC_QVCNT   8

// ws layout (bytes):
//   [0,    256)   float accumulators
//   [256,  260)   fmt int (0=int32, 1=uint8, 2=float32)
//   [320,  416)   cam_c uchar[96]
//   [25088,123392) qids int[24576]

__device__ __forceinline__ float block_sum256(float v, float* s_red) {
    #pragma unroll
    for (int off = 32; off > 0; off >>= 1) v += __shfl_xor(v, off, 64);
    __syncthreads();
    if ((threadIdx.x & 63) == 0) s_red[threadIdx.x >> 6] = v;
    __syncthreads();
    return s_red[0] + s_red[1] + s_red[2] + s_red[3];
}

// ---------------------------------------------------------------------------
// Kernel 0: detect bool storage format from the first 4096 bytes of
// target_mask (one uint4 per thread). float32 1.0f => byte3==0x3F (~512 hits
// in window); uint8 => nonzero bytes at misaligned offsets; int32 0/1 =>
// neither. Writes fmt to ws.
// ---------------------------------------------------------------------------
__global__ __launch_bounds__(256)
void k_detect(const uint4* __restrict__ tm_raw, int* __restrict__ fmt_p) {
    uint4 w = tm_raw[threadIdx.x];          // bytes [t*16, t*16+16)
    int cf = 0, cm = 0;
    unsigned int ws4[4] = {w.x, w.y, w.z, w.w};
    #pragma unroll
    for (int k = 0; k < 4; k++) {
        unsigned int u = ws4[k];
        cf += ((u >> 24) == 0x3Fu);
        cm += ((u & 0xFFFFFF00u) != 0u);
    }
    __shared__ int s_cf, s_cm;
    if (threadIdx.x == 0) { s_cf = 0; s_cm = 0; }
    __syncthreads();
    if (cf) atomicAdd(&s_cf, cf);
    if (cm) atomicAdd(&s_cm, cm);
    __syncthreads();
    if (threadIdx.x == 0)
        fmt_p[0] = (s_cf > 16) ? 2 : ((s_cm > 0) ? 1 : 0);
}

__device__ __forceinline__ int read_bool(const void* p, int idx, int fmt) {
    if (fmt == 2) return ((const float*)p)[idx] != 0.0f;
    if (fmt == 1) return ((const unsigned char*)p)[idx] != 0;
    return ((const int*)p)[idx] != 0;
}

// ---------------------------------------------------------------------------
// Kernel 1: per-(b,c) pack (stable targets-first order) + score/box/pair
// losses + qids + cam_c. One block of 256 per (b,c). Masks read raw per fmt.
// ---------------------------------------------------------------------------
__global__ __launch_bounds__(256)
void k_pack(const float* __restrict__ det_scores,
            const float* __restrict__ det_boxes,
            const float* __restrict__ assoc,
            const float* __restrict__ boxes,
            const void* __restrict__ cam_raw,
            const void* __restrict__ tm_raw,
            const int* __restrict__ ids,
            const int* __restrict__ img_h_p,
            const int* __restrict__ img_w_p,
            const int* __restrict__ fmt_p,
            unsigned char* __restrict__ cam_c,
            int* __restrict__ qids,
            float* __restrict__ acc) {
    const int bc = blockIdx.x;      // b*CC + c
    const int t = threadIdx.x;      // 0..255 (query index)
    __shared__ int s_scan[QQ];
    __shared__ int s_sids[QQ];
    __shared__ float s_red[4];

    const int fmt = fmt_p[0];
    const int cam = read_bool(cam_raw, bc, fmt);
    const int tm  = read_bool(tm_raw, bc * QQ + t, fmt);
    if (t == 0) cam_c[bc] = (unsigned char)cam;

    // inclusive prefix sum of tm (Hillis-Steele)
    s_scan[t] = tm;
    __syncthreads();
    for (int off = 1; off < QQ; off <<= 1) {
        int u = (t >= off) ? s_scan[t - off] : 0;
        __syncthreads();
        s_scan[t] += u;
        __syncthreads();
    }
    const int count = s_scan[QQ - 1];
    const int excl = s_scan[t] - tm;
    const int rank = tm ? excl : (count + (t - excl));   // stable partition rank

    // scatter sorted ids: sids[rank(q)] = ids[q]  (rank is a permutation)
    s_sids[rank] = ids[bc * QQ + t];
    __syncthreads();

    // thread t plays packed-slot j = t for score/pair, original-q = t for box
    const int j = t;
    const int qv = (j < count) && cam;
    const int qid = qv ? s_sids[j] : -1;
    qids[bc * QQ + j] = qid;

    float score_sum = 0.0f, box_sum = 0.0f, pair_sum = 0.0f;

    if (cam) {
        float p = det_scores[(size_t)bc * QQ + j];
        p = fminf(fmaxf(p, 1e-6f), 1.0f - 1e-6f);
        score_sum = (j < count) ? -__logf(p) : -__logf(1.0f - p);
    }
    if (qv) {
        int slot = qid & (TT - 1);          // qid >= 0, TT power of 2
        float a = assoc[((size_t)bc * QQ + j) * TT + slot];
        pair_sum = -__logf(fmaxf(a, 1e-8f));
    }
    if (tm && cam) {
        // this original query q=t landed at packed slot jj=rank
        const int jj = rank;
        const float iw = (float)img_w_p[0], ih = (float)img_h_p[0];
        const float* bx = boxes + ((size_t)bc * QQ + t) * 4;
        const float* db = det_boxes + ((size_t)bc * QQ + jj) * 4;
        float b0 = fminf(fmaxf(bx[0] / iw, 0.0f), 1.0f);
        float b1 = fminf(fmaxf(bx[1] / ih, 0.0f), 1.0f);
        float b2 = fminf(fmaxf(bx[2] / iw, 0.0f), 1.0f);
        float b3 = fminf(fmaxf(bx[3] / ih, 0.0f), 1.0f);
        box_sum = fabsf(db[0] - b0) + fabsf(db[1] - b1) +
                  fabsf(db[2] - b2) + fabsf(db[3] - b3);
    }

    float v;
    v = block_sum256(score_sum, s_red); if (t == 0) atomicAdd(&acc[ACC_SCORE], v);
    v = block_sum256(box_sum,   s_red); if (t == 0) atomicAdd(&acc[ACC_BOX], v);
    v = block_sum256(pair_sum,  s_red); if (t == 0) atomicAdd(&acc[ACC_PAIR], v);
    if (t == 0 && cam) {
        atomicAdd(&acc[ACC_CAMCNT], 1.0f);
        atomicAdd(&acc[ACC_QVCNT], (float)count);
    }
}

// ---------------------------------------------------------------------------
// Kernel 2: fused det_norm sum-of-squares + cam-masked entropy sum.
// Both arrays are B*C*Q*256 floats; float4 grid-stride.
// ---------------------------------------------------------------------------
__global__ __launch_bounds__(256)
void k_big(const float4* __restrict__ tok, const float4* __restrict__ asc,
           const unsigned char* __restrict__ cam_c, float* __restrict__ acc) {
    const long n4 = (long)BB * CC * QQ * DD / 4;   // 1572864
    float ss = 0.0f, ent = 0.0f;
    for (long i = (long)blockIdx.x * blockDim.x + threadIdx.x; i < n4;
         i += (long)gridDim.x * blockDim.x) {
        float4 tv = tok[i];
        ss += tv.x * tv.x + tv.y * tv.y + tv.z * tv.z + tv.w * tv.w;
        int bc = (int)(i >> 14);                   // (Q*T/4) = 16384 float4 per (b,c)
        if (cam_c[bc]) {
            float4 a = asc[i];
            ent -= a.x * __logf(fmaxf(a.x, 1e-8f));
            ent -= a.y * __logf(fmaxf(a.y, 1e-8f));
            ent -= a.z * __logf(fmaxf(a.z, 1e-8f));
            ent -= a.w * __logf(fmaxf(a.w, 1e-8f));
        }
    }
    __shared__ float s_red[4];
    float v;
    v = block_sum256(ss, s_red);  if (threadIdx.x == 0) atomicAdd(&acc[ACC_SS], v);
    v = block_sum256(ent, s_red); if (threadIdx.x == 0) atomicAdd(&acc[ACC_ENT], v);
}

// ---------------------------------------------------------------------------
// Kernel 3: consistency term. One block per (b, c<d pair); 4 waves, each
// wave owns q's strided by 4; lanes split T into float4s. Matches found by
// wave-wide ballot over qids of camera d.
// ---------------------------------------------------------------------------
__global__ __launch_bounds__(256)
void k_cons(const float* __restrict__ assoc, const int* __restrict__ qids,
            float* __restrict__ acc) {
    const int b = blockIdx.x / NPAIR;
    int pi = blockIdx.x % NPAIR;
    int c = 0, d = 1;
    {
        int k = pi;
        for (c = 0; c < CC - 1; c++) {
            int span = CC - 1 - c;
            if (k < span) { d = c + 1 + k; break; }
            k -= span;
        }
    }
    __shared__ int s_qc[QQ];
    __shared__ int s_qd[QQ];
    const int t = threadIdx.x;
    s_qc[t] = qids[(b * CC + c) * QQ + t];
    s_qd[t] = qids[(b * CC + d) * QQ + t];
    __syncthreads();

    const int lane = t & 63;
    const int wave = t >> 6;
    const int qd0 = s_qd[lane];
    const int qd1 = s_qd[64 + lane];
    const int qd2 = s_qd[128 + lane];
    const int qd3 = s_qd[192 + lane];
    const float4* assoc_c = (const float4*)(assoc + ((size_t)(b * CC + c) * QQ) * TT);
    const float4* assoc_d = (const float4*)(assoc + ((size_t)(b * CC + d) * QQ) * TT);

    float term_sum = 0.0f;
    int nval = 0;
    for (int q = wave; q < QQ; q += 4) {
        int id = s_qc[q];                       // wave-uniform
        if (id < 0) continue;
        unsigned long long m0 = __ballot(qd0 == id);
        unsigned long long m1 = __ballot(qd1 == id);
        unsigned long long m2 = __ballot(qd2 == id);
        unsigned long long m3 = __ballot(qd3 == id);
        int cnt = __popcll(m0) + __popcll(m1) + __popcll(m2) + __popcll(m3);
        if (cnt == 0) continue;
        float4 r = assoc_c[(size_t)q * (TT / 4) + lane];
        float ax = 0.0f, ay = 0.0f, az = 0.0f, aw = 0.0f;
        unsigned long long mm[4] = {m0, m1, m2, m3};
        #pragma unroll
        for (int kk = 0; kk < 4; kk++) {
            unsigned long long m = mm[kk];
            while (m) {
                int p = kk * 64 + __builtin_ctzll(m);
                m &= m - 1;
                float4 v = assoc_d[(size_t)p * (TT / 4) + lane];
                ax += v.x; ay += v.y; az += v.z; aw += v.w;
            }
        }
        float inv = 1.0f / (float)cnt;
        float dx = r.x - ax * inv, dy = r.y - ay * inv;
        float dz = r.z - az * inv, dw = r.w - aw * inv;
        float s = dx * dx + dy * dy + dz * dz + dw * dw;
        #pragma unroll
        for (int off = 32; off > 0; off >>= 1) s += __shfl_xor(s, off, 64);
        term_sum += s;
        nval++;
    }
    if (lane == 0) {
        atomicAdd(&acc[ACC_CONS], term_sum * (1.0f / TT));
        atomicAdd(&acc[ACC_CONSCNT], (float)nval);
    }
}

// ---------------------------------------------------------------------------
// Kernel 4: finalize — combine accumulators into the 6 outputs.
// ---------------------------------------------------------------------------
__global__ void k_fin(const float* __restrict__ acc, float* __restrict__ out) {
    float ss = acc[ACC_SS], ent = acc[ACC_ENT], score = acc[ACC_SCORE];
    float box = acc[ACC_BOX], pair = acc[ACC_PAIR], cons = acc[ACC_CONS];
    float conscnt = acc[ACC_CONSCNT], camcnt = acc[ACC_CAMCNT], qvcnt = acc[ACC_QVCNT];

    float det_norm = ss / (float)((long)BB * CC * QQ * DD);
    float denom_cam = fmaxf(camcnt * (float)QQ, 1.0f);
    float score_loss = score / denom_cam;
    float box_loss = box / fmaxf(4.0f * qvcnt, 1.0f);
    float det_sup = score_loss + box_loss;
    float ent_loss = ent / denom_cam;
    float pair_loss = pair / fmaxf(qvcnt, 1.0f);
    float cons_loss = cons / fmaxf(conscnt, 1.0f);
    float total = det_norm + det_sup + ent_loss + pair_loss + cons_loss;

    out[0] = total;
    out[1] = det_norm;
    out[2] = det_sup;
    out[3] = ent_loss;
    out[4] = pair_loss;
    out[5] = cons_loss;
}

extern "C" void kernel_launch(void* const* d_in, const int* in_sizes, int n_in,
                              void* d_out, int out_size, void* d_ws, size_t ws_size,
                              hipStream_t stream) {
    const float* det_tokens = (const float*)d_in[0];
    const float* det_scores = (const float*)d_in[1];
    const float* det_boxes  = (const float*)d_in[2];
    const float* assoc      = (const float*)d_in[3];
    const float* boxes      = (const float*)d_in[4];
    const void*  cam_raw    = d_in[5];
    const void*  tm_raw     = d_in[6];
    const int*   ids        = (const int*)d_in[7];
    const int*   img_h      = (const int*)d_in[8];
    const int*   img_w      = (const int*)d_in[9];

    float* acc = (float*)d_ws;
    int* fmt_p = (int*)((char*)d_ws + 256);
    unsigned char* cam_c = (unsigned char*)d_ws + 320;
    int* qids = (int*)((char*)d_ws + 25088);

    hipMemsetAsync(d_ws, 0, 256, stream);   // zero accumulators (ws is poisoned each call)

    k_detect<<<1, 256, 0, stream>>>((const uint4*)tm_raw, fmt_p);
    k_pack<<<BB * CC, 256, 0, stream>>>(det_scores, det_boxes, assoc, boxes,
                                        cam_raw, tm_raw, ids, img_h, img_w,
                                        fmt_p, cam_c, qids, acc);
    k_big<<<2048, 256, 0, stream>>>((const float4*)det_tokens, (const float4*)assoc,
                                    cam_c, acc);
    k_cons<<<BB * NPAIR, 256, 0, stream>>>(assoc, qids, acc);
    k_fin<<<1, 1, 0, stream>>>(acc, (float*)d_out);
}

// Round 3
// 120.184 us; speedup vs baseline: 1.8860x; 1.6534x over previous
//
#include <hip/hip_runtime.h>
#include <math.h>

#define BB 16
#define CC 6
#define QQ 256
#define TT 256
#define DD 256
#define NPAIR 15                  // C*(C-1)/2 for C=6
#define NBC (BB * CC)             // 96
#define BIG_BLOCKS (NBC * 16)     // 1536 (16 chunks of 1024 float4 per (b,c))
#define CONS_BLOCKS (BB * NPAIR * 4)  // 960 (4 q-groups per (b,pair))

// ws layout (bytes) — everything written unconditionally each call, no zeroing:
//   [0,      98304)  qids int[24576]
//   [98304,  98400)  cam_c uchar[96]
//   [98432, 101504)  packPart float[96*8]  (score,box,pair,qv,cam per block)
//   [101504,113792)  bigPart  float[1536*2] (ss, ent per block)
//   [113792,121472)  consPart float[960*2]  (cons, nval per block)

__device__ __forceinline__ float block_sum256(float v, float* s_red) {
    #pragma unroll
    for (int off = 32; off > 0; off >>= 1) v += __shfl_xor(v, off, 64);
    __syncthreads();
    if ((threadIdx.x & 63) == 0) s_red[threadIdx.x >> 6] = v;
    __syncthreads();
    return s_red[0] + s_red[1] + s_red[2] + s_red[3];
}

__device__ __forceinline__ int read_bool(const void* p, int idx, int fmt) {
    if (fmt == 2) return ((const float*)p)[idx] != 0.0f;
    if (fmt == 1) return ((const unsigned char*)p)[idx] != 0;
    return ((const int*)p)[idx] != 0;
}

// ---------------------------------------------------------------------------
// Kernel 1: per-(b,c) pack + score/box/pair losses + qids + cam_c.
// Each block redundantly detects the bool storage format from the first 4 KB
// of target_mask (valid window in every candidate format; L2-hot).
// ---------------------------------------------------------------------------
__global__ __launch_bounds__(256)
void k_pack(const float* __restrict__ det_scores,
            const float* __restrict__ det_boxes,
            const float* __restrict__ assoc,
            const float* __restrict__ boxes,
            const void* __restrict__ cam_raw,
            const void* __restrict__ tm_raw,
            const int* __restrict__ ids,
            const int* __restrict__ img_h_p,
            const int* __restrict__ img_w_p,
            unsigned char* __restrict__ cam_c,
            int* __restrict__ qids,
            float* __restrict__ packPart) {
    const int bc = blockIdx.x;      // b*CC + c
    const int t = threadIdx.x;      // 0..255 (query index)
    const int lane = t & 63, wv = t >> 6;
    __shared__ int s_cf, s_cm, s_wsum[4];
    __shared__ int s_sids[QQ];
    __shared__ float s_red[4];

    // --- format detection (first 4096 bytes of tm_raw) ---
    if (t == 0) { s_cf = 0; s_cm = 0; }
    __syncthreads();
    {
        uint4 w = ((const uint4*)tm_raw)[t];
        unsigned int u4[4] = {w.x, w.y, w.z, w.w};
        int cf = 0, cm = 0;
        #pragma unroll
        for (int k = 0; k < 4; k++) {
            cf += ((u4[k] >> 24) == 0x3Fu);          // 1.0f high byte
            cm += ((u4[k] & 0xFFFFFF00u) != 0u);     // nonzero misaligned byte
        }
        if (cf) atomicAdd(&s_cf, cf);
        if (cm) atomicAdd(&s_cm, cm);
    }
    __syncthreads();
    const int fmt = (s_cf > 16) ? 2 : ((s_cm > 0) ? 1 : 0);  // 2=f32 1=u8 0=i32

    const int cam = read_bool(cam_raw, bc, fmt);
    const int tm  = read_bool(tm_raw, bc * QQ + t, fmt);
    if (t == 0) cam_c[bc] = (unsigned char)cam;

    // --- stable targets-first rank via wave shfl-scan + LDS combine ---
    int v = tm;
    #pragma unroll
    for (int off = 1; off < 64; off <<= 1) {
        int u = __shfl_up(v, off, 64);
        if (lane >= off) v += u;
    }
    if (lane == 63) s_wsum[wv] = v;
    __syncthreads();
    const int count = s_wsum[0] + s_wsum[1] + s_wsum[2] + s_wsum[3];
    int woff = 0;
    #pragma unroll
    for (int k = 0; k < 3; k++) woff += (k < wv) ? s_wsum[k] : 0;
    const int excl = woff + v - tm;                      // exclusive scan of tm
    const int rank = tm ? excl : (count + (t - excl));   // stable partition rank

    s_sids[rank] = ids[bc * QQ + t];
    __syncthreads();

    // thread t plays packed-slot j = t for score/pair, original-q = t for box
    const int j = t;
    const int qv = (j < count) && cam;
    const int qid = qv ? s_sids[j] : -1;
    qids[bc * QQ + j] = qid;

    float score_sum = 0.0f, box_sum = 0.0f, pair_sum = 0.0f;

    if (cam) {
        float p = det_scores[(size_t)bc * QQ + j];
        p = fminf(fmaxf(p, 1e-6f), 1.0f - 1e-6f);
        score_sum = (j < count) ? -__logf(p) : -__logf(1.0f - p);
    }
    if (qv) {
        int slot = qid & (TT - 1);          // qid >= 0, TT power of 2
        float a = assoc[((size_t)bc * QQ + j) * TT + slot];
        pair_sum = -__logf(fmaxf(a, 1e-8f));
    }
    if (tm && cam) {
        const int jj = rank;                // packed slot of original query t
        const float iw = (float)img_w_p[0], ih = (float)img_h_p[0];
        const float* bx = boxes + ((size_t)bc * QQ + t) * 4;
        const float* db = det_boxes + ((size_t)bc * QQ + jj) * 4;
        float b0 = fminf(fmaxf(bx[0] / iw, 0.0f), 1.0f);
        float b1 = fminf(fmaxf(bx[1] / ih, 0.0f), 1.0f);
        float b2 = fminf(fmaxf(bx[2] / iw, 0.0f), 1.0f);
        float b3 = fminf(fmaxf(bx[3] / ih, 0.0f), 1.0f);
        box_sum = fabsf(db[0] - b0) + fabsf(db[1] - b1) +
                  fabsf(db[2] - b2) + fabsf(db[3] - b3);
    }

    float vs = block_sum256(score_sum, s_red);
    float vb = block_sum256(box_sum, s_red);
    float vp = block_sum256(pair_sum, s_red);
    if (t == 0) {
        float* row = packPart + bc * 8;
        row[0] = vs; row[1] = vb; row[2] = vp;
        row[3] = cam ? (float)count : 0.0f;   // qvalid count
        row[4] = (float)cam;
    }
}

// ---------------------------------------------------------------------------
// Kernel 2: fused det_norm sum-of-squares + cam-masked entropy sum.
// One block per 1024-float4 chunk within one (b,c): cam is block-uniform,
// 8 independent 16B loads per thread, fully unrolled.
// ---------------------------------------------------------------------------
__global__ __launch_bounds__(256)
void k_big(const float4* __restrict__ tok, const float4* __restrict__ asc,
           const unsigned char* __restrict__ cam_c, float* __restrict__ bigPart) {
    const int blk = blockIdx.x;
    const int bc = blk >> 4;
    const int t = threadIdx.x;
    const long base = (long)bc * 16384 + (long)(blk & 15) * 1024 + t;

    float4 t0 = tok[base], t1 = tok[base + 256],
           t2 = tok[base + 512], t3 = tok[base + 768];
    float ss = t0.x * t0.x + t0.y * t0.y + t0.z * t0.z + t0.w * t0.w
             + t1.x * t1.x + t1.y * t1.y + t1.z * t1.z + t1.w * t1.w
             + t2.x * t2.x + t2.y * t2.y + t2.z * t2.z + t2.w * t2.w
             + t3.x * t3.x + t3.y * t3.y + t3.z * t3.z + t3.w * t3.w;

    float ent = 0.0f;
    if (cam_c[bc]) {                      // block-uniform branch
        float4 a0 = asc[base], a1 = asc[base + 256],
               a2 = asc[base + 512], a3 = asc[base + 768];
        ent -= a0.x * __logf(fmaxf(a0.x, 1e-8f)) + a0.y * __logf(fmaxf(a0.y, 1e-8f))
             + a0.z * __logf(fmaxf(a0.z, 1e-8f)) + a0.w * __logf(fmaxf(a0.w, 1e-8f));
        ent -= a1.x * __logf(fmaxf(a1.x, 1e-8f)) + a1.y * __logf(fmaxf(a1.y, 1e-8f))
             + a1.z * __logf(fmaxf(a1.z, 1e-8f)) + a1.w * __logf(fmaxf(a1.w, 1e-8f));
        ent -= a2.x * __logf(fmaxf(a2.x, 1e-8f)) + a2.y * __logf(fmaxf(a2.y, 1e-8f))
             + a2.z * __logf(fmaxf(a2.z, 1e-8f)) + a2.w * __logf(fmaxf(a2.w, 1e-8f));
        ent -= a3.x * __logf(fmaxf(a3.x, 1e-8f)) + a3.y * __logf(fmaxf(a3.y, 1e-8f))
             + a3.z * __logf(fmaxf(a3.z, 1e-8f)) + a3.w * __logf(fmaxf(a3.w, 1e-8f));
    }

    __shared__ float s_red[4];
    float vss = block_sum256(ss, s_red);
    float vent = block_sum256(ent, s_red);
    if (t == 0) { bigPart[blk * 2] = vss; bigPart[blk * 2 + 1] = vent; }
}

// ---------------------------------------------------------------------------
// Kernel 3: consistency term. One block per (b, pair, qgroup-of-64); each
// wave walks 16 q's. Per-q cross-lane reduce hoisted out of the loop
// (sum over q and lanes commute).
// ---------------------------------------------------------------------------
__global__ __launch_bounds__(256)
void k_cons(const float* __restrict__ assoc, const int* __restrict__ qids,
            float* __restrict__ consPart) {
    const int blk = blockIdx.x;
    const int qg = blk & 3;
    const int bp = blk >> 2;            // b*NPAIR + pair
    const int b = bp / NPAIR;
    int pi = bp % NPAIR;
    int c = 0, d = 1;
    {
        int k = pi;
        for (c = 0; c < CC - 1; c++) {
            int span = CC - 1 - c;
            if (k < span) { d = c + 1 + k; break; }
            k -= span;
        }
    }
    const int t = threadIdx.x, lane = t & 63, wv = t >> 6;
    __shared__ int s_qc[64];
    __shared__ int s_qd[QQ];
    __shared__ float s_wred[4];
    __shared__ int s_wnval[4];
    if (t < 64) s_qc[t] = qids[(b * CC + c) * QQ + qg * 64 + t];
    s_qd[t] = qids[(b * CC + d) * QQ + t];
    __syncthreads();

    const int qd0 = s_qd[lane];
    const int qd1 = s_qd[64 + lane];
    const int qd2 = s_qd[128 + lane];
    const int qd3 = s_qd[192 + lane];
    const float4* assoc_c = (const float4*)(assoc + (size_t)(b * CC + c) * QQ * TT);
    const float4* assoc_d = (const float4*)(assoc + (size_t)(b * CC + d) * QQ * TT);

    float tot = 0.0f;
    int nval = 0;
    for (int qi = 0; qi < 16; qi++) {
        const int qloc = wv * 16 + qi;
        const int id = s_qc[qloc];          // wave-uniform
        if (id < 0) continue;
        unsigned long long m0 = __ballot(qd0 == id);
        unsigned long long m1 = __ballot(qd1 == id);
        unsigned long long m2 = __ballot(qd2 == id);
        unsigned long long m3 = __ballot(qd3 == id);
        int cnt = __popcll(m0) + __popcll(m1) + __popcll(m2) + __popcll(m3);
        if (cnt == 0) continue;
        const int q = qg * 64 + qloc;
        float4 r = assoc_c[(size_t)q * (TT / 4) + lane];
        float ax = 0.0f, ay = 0.0f, az = 0.0f, aw = 0.0f;
        unsigned long long mm[4] = {m0, m1, m2, m3};
        #pragma unroll
        for (int kk = 0; kk < 4; kk++) {
            unsigned long long m = mm[kk];
            while (m) {
                int p = kk * 64 + __builtin_ctzll(m);
                m &= m - 1;
                float4 vv = assoc_d[(size_t)p * (TT / 4) + lane];
                ax += vv.x; ay += vv.y; az += vv.z; aw += vv.w;
            }
        }
        float inv = 1.0f / (float)cnt;
        float dx = r.x - ax * inv, dy = r.y - ay * inv;
        float dz = r.z - az * inv, dw = r.w - aw * inv;
        tot += dx * dx + dy * dy + dz * dz + dw * dw;
        nval++;
    }
    #pragma unroll
    for (int off = 32; off > 0; off >>= 1) tot += __shfl_xor(tot, off, 64);
    if (lane == 0) { s_wred[wv] = tot; s_wnval[wv] = nval; }
    __syncthreads();
    if (t == 0) {
        float csum = s_wred[0] + s_wred[1] + s_wred[2] + s_wred[3];
        int n4 = s_wnval[0] + s_wnval[1] + s_wnval[2] + s_wnval[3];
        consPart[blk * 2] = csum * (1.0f / TT);
        consPart[blk * 2 + 1] = (float)n4;
    }
}

// ---------------------------------------------------------------------------
// Kernel 4: finalize — sum all per-block partials, emit the 6 outputs.
// ---------------------------------------------------------------------------
__global__ __launch_bounds__(256)
void k_fin(const float* __restrict__ packPart, const float* __restrict__ bigPart,
           const float* __restrict__ consPart, float* __restrict__ out) {
    const int t = threadIdx.x;
    __shared__ float s_red[4];
    float sc = 0, bx = 0, pr = 0, qv = 0, cm = 0;
    if (t < NBC) {
        const float* row = packPart + t * 8;
        sc = row[0]; bx = row[1]; pr = row[2]; qv = row[3]; cm = row[4];
    }
    float ss = 0, ent = 0;
    for (int i = t; i < BIG_BLOCKS; i += 256) {
        ss += bigPart[2 * i]; ent += bigPart[2 * i + 1];
    }
    float cons = 0, nval = 0;
    for (int i = t; i < CONS_BLOCKS; i += 256) {
        cons += consPart[2 * i]; nval += consPart[2 * i + 1];
    }
    sc = block_sum256(sc, s_red);
    bx = block_sum256(bx, s_red);
    pr = block_sum256(pr, s_red);
    qv = block_sum256(qv, s_red);
    cm = block_sum256(cm, s_red);
    ss = block_sum256(ss, s_red);
    ent = block_sum256(ent, s_red);
    cons = block_sum256(cons, s_red);
    nval = block_sum256(nval, s_red);
    if (t == 0) {
        float det_norm = ss / (float)((long)BB * CC * QQ * DD);
        float denom_cam = fmaxf(cm * (float)QQ, 1.0f);
        float score_loss = sc / denom_cam;
        float box_loss = bx / fmaxf(4.0f * qv, 1.0f);
        float det_sup = score_loss + box_loss;
        float ent_loss = ent / denom_cam;
        float pair_loss = pr / fmaxf(qv, 1.0f);
        float cons_loss = cons / fmaxf(nval, 1.0f);
        out[0] = det_norm + det_sup + ent_loss + pair_loss + cons_loss;
        out[1] = det_norm;
        out[2] = det_sup;
        out[3] = ent_loss;
        out[4] = pair_loss;
        out[5] = cons_loss;
    }
}

extern "C" void kernel_launch(void* const* d_in, const int* in_sizes, int n_in,
                              void* d_out, int out_size, void* d_ws, size_t ws_size,
                              hipStream_t stream) {
    const float* det_tokens = (const float*)d_in[0];
    const float* det_scores = (const float*)d_in[1];
    const float* det_boxes  = (const float*)d_in[2];
    const float* assoc      = (const float*)d_in[3];
    const float* boxes      = (const float*)d_in[4];
    const void*  cam_raw    = d_in[5];
    const void*  tm_raw     = d_in[6];
    const int*   ids        = (const int*)d_in[7];
    const int*   img_h      = (const int*)d_in[8];
    const int*   img_w      = (const int*)d_in[9];

    char* ws = (char*)d_ws;
    int* qids            = (int*)(ws + 0);
    unsigned char* cam_c = (unsigned char*)(ws + 98304);
    float* packPart      = (float*)(ws + 98432);
    float* bigPart       = (float*)(ws + 101504);
    float* consPart      = (float*)(ws + 113792);

    k_pack<<<NBC, 256, 0, stream>>>(det_scores, det_boxes, assoc, boxes,
                                    cam_raw, tm_raw, ids, img_h, img_w,
                                    cam_c, qids, packPart);
    k_big<<<BIG_BLOCKS, 256, 0, stream>>>((const float4*)det_tokens,
                                          (const float4*)assoc, cam_c, bigPart);
    k_cons<<<CONS_BLOCKS, 256, 0, stream>>>(assoc, qids, consPart);
    k_fin<<<1, 256, 0, stream>>>(packPart, bigPart, consPart, (float*)d_out);
}